// Round 6
// baseline (536.697 us; speedup 1.0000x reference)
//
#include <hip/hip_runtime.h>
#include <hip/hip_bf16.h>
#include <math.h>

// Problem constants
#define B_    1024
#define D_    512
#define V_    100000
#define NT_   782             // n-tiles of 128 (782*128 = 100096)
#define EPS_  1e-7f
#define COSM  0.9210609940028851f   // cos(0.4)
#define SINM  0.3894183423086505f   // sin(0.4)

typedef __bf16 bf16x8 __attribute__((ext_vector_type(8)));
typedef float  f32x4  __attribute__((ext_vector_type(4)));

struct alignas(16) US8 { unsigned short h[8]; };

// round-to-nearest-even float -> bf16 bits (inputs finite)
__device__ __forceinline__ unsigned short f2bf(float f) {
  union { float f; unsigned u; } a; a.f = f;
  unsigned u = a.u;
  u += 0x7FFFu + ((u >> 16) & 1u);
  return (unsigned short)(u >> 16);
}

__device__ __forceinline__ void async_copy16(void* lds, const void* g) {
  __builtin_amdgcn_global_load_lds(
      (const __attribute__((address_space(1))) void*)g,
      (__attribute__((address_space(3))) void*)lds, 16, 0, 0);
}

// ---------------------------------------------------------------------------
// Kernel 1: L2-normalize rows of x -> bf16; zero S.
// ---------------------------------------------------------------------------
__global__ void x_prep(const float* __restrict__ x,
                       unsigned short* __restrict__ xb,
                       float* __restrict__ S) {
  int t = threadIdx.x;
  int lane = t & 63, wave = t >> 6;
  int row = blockIdx.x * 4 + wave;
  const float* xr = x + (size_t)row * D_;
  f32x4 a = *(const f32x4*)(xr + lane * 8);
  f32x4 b = *(const f32x4*)(xr + lane * 8 + 4);
  float ss = a[0]*a[0] + a[1]*a[1] + a[2]*a[2] + a[3]*a[3]
           + b[0]*b[0] + b[1]*b[1] + b[2]*b[2] + b[3]*b[3];
#pragma unroll
  for (int off = 32; off > 0; off >>= 1) ss += __shfl_xor(ss, off, 64);
  float inv = 1.0f / fmaxf(sqrtf(ss), 1e-12f);
  US8 pk;
#pragma unroll
  for (int j = 0; j < 4; ++j) pk.h[j]     = f2bf(a[j] * inv);
#pragma unroll
  for (int j = 0; j < 4; ++j) pk.h[4 + j] = f2bf(b[j] * inv);
  *(US8*)(xb + (size_t)row * D_ + lane * 8) = pk;
  if (lane == 0) S[row] = 0.0f;
}

// ---------------------------------------------------------------------------
// Kernel 2 (fused): 128x128 bf16 MFMA GEMM reading B straight from fp32 w.
// Write-conflict fix: per write-instruction j, thread t writes column
// cc = (j + (t>>1)) & 3 -> within each 16-lane LDS phase col&7 covers all 8
// values twice (2-way = free).  Half-tile register prefetch: next iter's
// rows 0-3 issued before the MFMA section (latency covered by MFMA).
// ---------------------------------------------------------------------------
#define BM 128
#define BN 128
#define BK 64

__global__ __launch_bounds__(256) void gemm_fused(
    const unsigned short* __restrict__ xb,
    const float* __restrict__ w,
    const int* __restrict__ labels,
    float* __restrict__ S, float* __restrict__ Lb) {
  int bid = blockIdx.x;
  int xcd = bid & 7;
  int slot = bid >> 3;          // 0..783
  int tn = xcd * 98 + (slot >> 3);
  int tm = slot & 7;
  if (tn >= NT_) return;
  int m0 = tm * BM, n0 = tn * BN;

  // LDS slot p (16B chunks) holds (m = p>>3, kc = (p&7) ^ (m&7))
  __shared__ unsigned short Ab[BM * BK];  // 16 KB
  __shared__ unsigned short Bb[BN * BK];  // 16 KB
  __shared__ float sqred[8][BN];          // 4 KB
  __shared__ float iwL[BN];
  __shared__ int labT[BM];
  int t = threadIdx.x;
  if (t < BM) labT[t] = labels[m0 + t];
  int lane = t & 63;
  int q = lane >> 4, l15 = lane & 15;
  int wave = t >> 6;
  int wm = (wave & 1) * 64, wn = (wave >> 1) * 64;
  f32x4 acc[4][4] = {};

  // ---- A staging (async DMA, proven) ----
  const unsigned short* gA[4];
  unsigned short* lA[4];
#pragma unroll
  for (int j = 0; j < 4; ++j) {
    int p = t + 256 * j;
    int m = p >> 3;
    int kc = (p & 7) ^ (m & 7);
    gA[j] = xb + (size_t)(m0 + m) * D_ + kc * 8;
    lA[j] = Ab + p * 8;
  }

  // ---- B staging: thread owns cols [c0l,c0l+4) x k-rows [rp*8, rp*8+8) ----
  int cg = t & 31;
  int rp = t >> 5;              // chunk index within BK tile
  int c0l = cg * 4;
  bool vok = (n0 + c0l + 3) < V_;   // all-or-nothing (V_ % 4 == 0)
  const float* wb = w + (size_t)rp * 8 * V_ + n0 + c0l;
  int ccrot = (t >> 1) & 3;     // per-thread cc rotation
  float ssq[4] = {0.0f, 0.0f, 0.0f, 0.0f};

  // prologue: prefetch rows 0-3 of iter 0
  f32x4 lo[4];
  if (vok) {
#pragma unroll
    for (int i = 0; i < 4; ++i) lo[i] = *(const f32x4*)(wb + (size_t)i * V_);
  } else {
#pragma unroll
    for (int i = 0; i < 4; ++i) lo[i] = f32x4{0.0f, 0.0f, 0.0f, 0.0f};
  }

  for (int kt = 0; kt < D_; kt += BK) {
    // load rows 4-7 of this iter
    f32x4 hi[4];
    if (vok) {
#pragma unroll
      for (int i = 0; i < 4; ++i)
        hi[i] = *(const f32x4*)(wb + (size_t)(4 + i) * V_);
    } else {
#pragma unroll
      for (int i = 0; i < 4; ++i) hi[i] = f32x4{0.0f, 0.0f, 0.0f, 0.0f};
    }
#pragma unroll
    for (int j = 0; j < 4; ++j) async_copy16(lA[j], gA[j] + kt);

    // pack + conflict-free rotated writes
#pragma unroll
    for (int j = 0; j < 4; ++j) {
      int cc = (j + ccrot) & 3;
      int col = c0l + cc;
      US8 pk;
#pragma unroll
      for (int i = 0; i < 4; ++i) {
        float v = lo[i][cc];
        ssq[cc] += v * v;
        pk.h[i] = f2bf(v);
      }
#pragma unroll
      for (int i = 0; i < 4; ++i) {
        float v = hi[i][cc];
        ssq[cc] += v * v;
        pk.h[4 + i] = f2bf(v);
      }
      *(US8*)&Bb[(col * 8 + (rp ^ (col & 7))) * 8] = pk;
    }
    __syncthreads();

    // prefetch rows 0-3 of NEXT iter (latency covered by MFMA below)
    const float* wbn = wb + (size_t)BK * V_;
    if (kt + BK < D_) {
      if (vok) {
#pragma unroll
        for (int i = 0; i < 4; ++i)
          lo[i] = *(const f32x4*)(wbn + (size_t)i * V_);
      }
    }
    wb = wbn;

    int h = l15 & 7;
#pragma unroll
    for (int s = 0; s < 2; ++s) {
      int kx = s * 4 + q;
      bf16x8 af[4], bfr[4];
#pragma unroll
      for (int ri = 0; ri < 4; ++ri) {
        int row_ = wm + ri * 16 + l15;
        af[ri] = *(const bf16x8*)&Ab[(row_ * 8 + (kx ^ h)) * 8];
      }
#pragma unroll
      for (int ci = 0; ci < 4; ++ci) {
        int row_ = wn + ci * 16 + l15;
        bfr[ci] = *(const bf16x8*)&Bb[(row_ * 8 + (kx ^ h)) * 8];
      }
#pragma unroll
      for (int ri = 0; ri < 4; ++ri)
#pragma unroll
        for (int ci = 0; ci < 4; ++ci)
          acc[ri][ci] = __builtin_amdgcn_mfma_f32_16x16x32_bf16(
              af[ri], bfr[ci], acc[ri][ci], 0, 0, 0);
    }
    __syncthreads();
  }

  // ---- column inv-norms: LDS reduce over the 8 row-parts ----
#pragma unroll
  for (int cc = 0; cc < 4; ++cc) sqred[rp][c0l + cc] = ssq[cc];
  __syncthreads();
  if (t < BN) {
    float tot = 0.0f;
#pragma unroll
    for (int p = 0; p < 8; ++p) tot += sqred[p][t];
    iwL[t] = ((n0 + t) < V_) ? 1.0f / fmaxf(sqrtf(tot), 1e-12f) : 0.0f;
  }
  __syncthreads();

  // ---- epilogue: C/D layout col = lane&15 (n side), row = q*4 + reg ----
  float iw[4]; int vcol[4];
#pragma unroll
  for (int ci = 0; ci < 4; ++ci) {
    int nl = wn + ci * 16 + l15;
    vcol[ci] = n0 + nl;
    iw[ci] = iwL[nl];
  }
#pragma unroll
  for (int ri = 0; ri < 4; ++ri) {
#pragma unroll
    for (int reg = 0; reg < 4; ++reg) {
      int ml = wm + ri * 16 + q * 4 + reg;
      int r = m0 + ml;
      int lab = labT[ml];
      float s = 0.0f;
#pragma unroll
      for (int ci = 0; ci < 4; ++ci) {
        float cv = acc[ri][ci][reg] * iw[ci];
        cv = fminf(fmaxf(cv, -1.0f + EPS_), 1.0f - EPS_);
        float logit = cv;
        if (vcol[ci] == lab) {
          logit = cv * COSM - sqrtf(fmaxf(1.0f - cv * cv, 0.0f)) * SINM;
          Lb[r] = logit;               // unique writer across grid
        }
        s += (vcol[ci] < V_) ? __expf(logit) : 0.0f;
      }
      s += __shfl_xor(s, 1, 64);
      s += __shfl_xor(s, 2, 64);
      s += __shfl_xor(s, 4, 64);
      s += __shfl_xor(s, 8, 64);
      if (l15 == 0) atomicAdd(&S[r], s);
    }
  }
}

// ---------------------------------------------------------------------------
// Kernel 3: loss = mean(log(S) - label_logit)
// ---------------------------------------------------------------------------
__global__ void finalk(const float* __restrict__ S, const float* __restrict__ Lb,
                       float* __restrict__ out) {
  __shared__ float red[256];
  int t = threadIdx.x;
  float s = 0.0f;
  for (int i = t; i < B_; i += 256) s += logf(S[i]) - Lb[i];
  red[t] = s;
  __syncthreads();
  for (int o = 128; o > 0; o >>= 1) {
    if (t < o) red[t] += red[t + o];
    __syncthreads();
  }
  if (t == 0) out[0] = red[0] * (1.0f / B_);
}

// ---------------------------------------------------------------------------
extern "C" void kernel_launch(void* const* d_in, const int* in_sizes, int n_in,
                              void* d_out, int out_size, void* d_ws, size_t ws_size,
                              hipStream_t stream) {
  const float* x = (const float*)d_in[0];
  const float* w = (const float*)d_in[1];
  const int* labels = (const int*)d_in[2];
  float* out = (float*)d_out;
  char* ws = (char*)d_ws;
  // ws layout (16B-aligned):
  //   xb : 1024*512 bf16 = 1,048,576 B
  //   S  : 1024 f32, Lb : 1024 f32
  unsigned short* xb = (unsigned short*)ws;
  float* S  = (float*)(ws + 1048576ull);
  float* Lb = (float*)(ws + 1052672ull);

  x_prep<<<256, 256, 0, stream>>>(x, xb, S);
  gemm_fused<<<6272, 256, 0, stream>>>(xb, w, labels, S, Lb);
  finalk<<<1, 256, 0, stream>>>(S, Lb, out);
}